// Round 7
// baseline (492.222 us; speedup 1.0000x reference)
//
#include <hip/hip_runtime.h>
#include <math.h>

#define NC 19683
#define KN 26
#define DD 128
#define HGN 64
#define LDSB 136
#define DTC 0.1f
#define CPW 8          // kE: cells per wave
#define CPB 32         // kE: cells per block (4 waves x 8)
#define SLOTB 13312    // 26 rows * 512 B

using bf8v = __attribute__((ext_vector_type(8))) short;
using f4v  = __attribute__((ext_vector_type(4))) float;

typedef __attribute__((address_space(1))) const void g_void;
typedef __attribute__((address_space(3))) void l_void;

#define WAITV(N) asm volatile("s_waitcnt vmcnt(" #N ")" ::: "memory")

static __device__ __forceinline__ unsigned short f2bf(float x) {
    union { float f; unsigned u; } v; v.f = x;
    unsigned r = v.u + 0x7fffu + ((v.u >> 16) & 1u);
    return (unsigned short)(r >> 16);
}
static __device__ __forceinline__ unsigned pk2(float a, float b) {
    return ((unsigned)f2bf(a)) | (((unsigned)f2bf(b)) << 16);
}
// pack 8 f32 (two float4) -> bf8v via v_cvt_pk_bf16_f32 (RNE, matches f2bf)
static __device__ __forceinline__ bf8v cvt8(float4 lo, float4 hi) {
    union { bf8v v; unsigned d[4]; } u;
    asm volatile("v_cvt_pk_bf16_f32 %0, %1, %2" : "=v"(u.d[0]) : "v"(lo.x), "v"(lo.y));
    asm volatile("v_cvt_pk_bf16_f32 %0, %1, %2" : "=v"(u.d[1]) : "v"(lo.z), "v"(lo.w));
    asm volatile("v_cvt_pk_bf16_f32 %0, %1, %2" : "=v"(u.d[2]) : "v"(hi.x), "v"(hi.y));
    asm volatile("v_cvt_pk_bf16_f32 %0, %1, %2" : "=v"(u.d[3]) : "v"(hi.z), "v"(hi.w));
    return u.v;
}

// ---------------- prep: transpose 4x [256,128] f32 weights -> [128][256] bf16; Wg1 -> [64][128] bf16 ----
__global__ __launch_bounds__(256) void k_prep(const float* __restrict__ Wl,
    const float* __restrict__ Wm, const float* __restrict__ Wu,
    const float* __restrict__ Wc, const float* __restrict__ Wg1,
    unsigned short* __restrict__ WT, unsigned short* __restrict__ WgT)
{
    int idx = blockIdx.x * 256 + threadIdx.x;   // 544*256 = 139264 exact
    if (idx < 131072) {
        int m = idx >> 15;
        int r = idx & 32767;
        int j = r >> 8;     // 0..127 output col
        int i = r & 255;    // 0..255 k
        const float* src = (m == 0) ? Wl : (m == 1) ? Wm : (m == 2) ? Wu : Wc;
        WT[idx] = f2bf(src[i * DD + j]);
    } else {
        int idx2 = idx - 131072;        // 0..8191
        int col = idx2 >> 7;            // 0..63
        int k = idx2 & 127;             // 0..127
        WgT[idx2] = f2bf(Wg1[k * HGN + col]);
    }
}

// ---------------- kE: P + edge pass. DMA-staged (global_load_lds) wave-private cell loop ----------------
// LDS arena: [0,106496)  8 slots (4 waves x 2) of 26x512B f32 nbr rows, XOR-swizzled
//            [106496,122880) Pbuf f32[32][128]
//            [122880,157696) Wt  Wm2 bf16 [128][LDSB]
__global__ __launch_bounds__(256, 1) void kE(const float* __restrict__ cur,
    const float* __restrict__ nbr, const int* __restrict__ conn,
    const unsigned short* __restrict__ WT, const float* __restrict__ b_msg,
    unsigned short* __restrict__ agg_l, unsigned short* __restrict__ agg_m,
    unsigned short* __restrict__ agg_d)
{
    __shared__ __align__(16) char LDSA[157696];
    float* Pb = (float*)(LDSA + 106496);
    unsigned short* Wt = (unsigned short*)(LDSA + 122880);

    int t = threadIdx.x;
    int n0 = blockIdx.x * CPB;
    int w = t >> 6, lane = t & 63;
    int lm = lane & 15, lq = lane >> 4;
    int cw0 = n0 + w * CPW;

    // ---- conn prefetch for this wave's 8 cells (regs) ----
    int ctv[CPW];
    #pragma unroll
    for (int i = 0; i < CPW; ++i) {
        int n = cw0 + i;
        ctv[i] = (n < NC && lane < KN) ? conn[(size_t)n * KN + lane] : 3;
    }

    // ---- stage Wt <- Wm2 (bf16, pitch LDSB) ----
    {
        const unsigned short* Wm2 = WT + 32768 + 128;
        for (int p = 0; p < 8; ++p) {
            int ch = p * 256 + t;
            int j = ch >> 4, i8 = (ch & 15) * 8;
            *(bf8v*)&Wt[j * LDSB + i8] = *(const bf8v*)&Wm2[j * 256 + i8];
        }
    }

    // ---- P-pass: A-frags straight from global cur (+cvt), B from global Wm1; Pbuf f32 ----
    {
        const unsigned short* Wm1 = WT + 32768;
        bf8v afrP[2][4];
        #pragma unroll
        for (int mt2 = 0; mt2 < 2; ++mt2) {
            int gr = n0 + mt2 * 16 + lm;
            if (gr >= NC) gr = NC - 1;
            const float* rb = &cur[(size_t)gr * DD];
            #pragma unroll
            for (int s = 0; s < 4; ++s) {
                float4 lo = *(const float4*)&rb[s * 32 + lq * 8];
                float4 hi = *(const float4*)&rb[s * 32 + lq * 8 + 4];
                afrP[mt2][s] = cvt8(lo, hi);
            }
        }
        for (int nt = 0; nt < 2; ++nt) {
            int col0 = w * 32 + nt * 16;
            float bm = b_msg[col0 + lm];
            const unsigned short* bb = &Wm1[(col0 + lm) * 256 + lq * 8];
            for (int mt2 = 0; mt2 < 2; ++mt2) {
                f4v acc = {0.f, 0.f, 0.f, 0.f};
                #pragma unroll
                for (int s = 0; s < 4; ++s) {
                    bf8v b = *(const bf8v*)&bb[s * 32];
                    acc = __builtin_amdgcn_mfma_f32_16x16x32_bf16(afrP[mt2][s], b, acc, 0, 0, 0);
                }
                for (int r = 0; r < 4; ++r) {
                    int row = mt2 * 16 + lq * 4 + r;
                    Pb[row * DD + col0 + lm] = acc[r] + bm;
                }
            }
        }
    }
    __syncthreads();    // Wt + Pbuf ready; compiler drains vmcnt(0) here -> clean DMA counting

    // ---- DMA stage: 13 x 1KB global_load_lds into my slot (i&1); source pre-swizzled ----
    int rlo = lane >> 5;                        // sub-row within instr
    unsigned wb = (unsigned)(lane & 31) * 16;   // within-row byte
    auto stage = [&](int i) {
        int nn = cw0 + i; if (nn >= NC) nn = NC - 1;
        const char* cellbase = (const char*)(nbr + (size_t)nn * KN * DD);
        char* slot = LDSA + (size_t)(w * 2 + (i & 1)) * SLOTB;
        #pragma unroll
        for (int j = 0; j < 13; ++j) {
            int row = 2 * j + rlo;
            const char* src = cellbase + (size_t)row * 512 + (wb ^ ((unsigned)(row & 7) << 4));
            __builtin_amdgcn_global_load_lds((g_void*)src, (l_void*)(slot + j * 1024), 16, 0, 0);
        }
    };

    stage(0);
    for (int i = 0; i < CPW; ++i) {
        int n = cw0 + i;
        if (n >= NC) break;                     // wave-uniform
        if (i + 1 < CPW) stage(i + 1);
        // wait slot i complete: newest-allowed = loads(i+1)=13 (+ stores(i-1)=10 when present)
        if (i == 0) WAITV(13);
        else if (i + 1 < CPW) WAITV(23);
        else WAITV(10);
        __builtin_amdgcn_sched_barrier(0);

        const char* slot = LDSA + (size_t)(w * 2 + (i & 1)) * SLOTB;
        int ct = ctv[i];
        unsigned long long mlb = __ballot(ct == 0);
        unsigned long long mfb = __ballot(ct == 1);
        unsigned long long mdb = __ballot(ct == 2);
        float icl = 1.f / fmaxf((float)__builtin_popcountll(mlb), 1.f);
        float icf = 1.f / fmaxf((float)__builtin_popcountll(mfb), 1.f);
        float icd = 1.f / fmaxf((float)__builtin_popcountll(mdb), 1.f);

        // ---- masked column sums from slot (lane owns cols 2*lane, 2*lane+1) ----
        float slx = 0.f, sly = 0.f, sdx = 0.f, sdy = 0.f;
        #pragma unroll
        for (int k = 0; k < KN; ++k) {
            float2 v = *(const float2*)(slot + (size_t)k * 512 + (((unsigned)lane * 8) ^ ((unsigned)(k & 7) << 4)));
            if ((mlb >> k) & 1) { slx += v.x; sly += v.y; }
            if ((mdb >> k) & 1) { sdx += v.x; sdy += v.y; }
        }
        *(unsigned*)&agg_l[(size_t)n * DD + lane * 2] = pk2(slx * icl, sly * icl);
        *(unsigned*)&agg_d[(size_t)n * DD + lane * 2] = pk2(sdx * icd, sdy * icd);

        // ---- A-fragments from slot (swizzled) + cvt ----
        bf8v afr[2][4];
        #pragma unroll
        for (int mt2 = 0; mt2 < 2; ++mt2) {
            int row = mt2 * 16 + lm;                 // rows 26..31 read pad (masked by mfb)
            unsigned X = (unsigned)(row & 7) << 4;
            const char* rb = slot + (size_t)row * 512;
            #pragma unroll
            for (int s = 0; s < 4; ++s) {
                unsigned b0 = (unsigned)(s * 128 + lq * 32);
                float4 lo = *(const float4*)(rb + (b0 ^ X));
                float4 hi = *(const float4*)(rb + ((b0 + 16) ^ X));
                afr[mt2][s] = cvt8(lo, hi);
            }
        }

        // ---- 8 col-tiles MFMA + masked relu-sum ----
        int prow = (w * CPW + i) * DD;
        #pragma unroll
        for (int nt = 0; nt < 8; ++nt) {
            float pv = Pb[prow + nt * 16 + lm];
            f4v a0 = {0.f, 0.f, 0.f, 0.f}, a1 = {0.f, 0.f, 0.f, 0.f};
            #pragma unroll
            for (int s = 0; s < 4; ++s) {
                bf8v b = *(const bf8v*)&Wt[(nt * 16 + lm) * LDSB + s * 32 + lq * 8];
                a0 = __builtin_amdgcn_mfma_f32_16x16x32_bf16(afr[0][s], b, a0, 0, 0, 0);
                a1 = __builtin_amdgcn_mfma_f32_16x16x32_bf16(afr[1][s], b, a1, 0, 0, 0);
            }
            float msum = 0.f;
            #pragma unroll
            for (int r = 0; r < 4; ++r) {
                int rr = lq * 4 + r;
                if ((mfb >> rr) & 1) msum += fmaxf(pv + a0[r], 0.f);
                int rr2 = 16 + lq * 4 + r;
                if ((mfb >> rr2) & 1) msum += fmaxf(pv + a1[r], 0.f);
            }
            msum += __shfl_xor(msum, 16, 64);
            msum += __shfl_xor(msum, 32, 64);
            if (lane < 16) agg_m[(size_t)n * DD + nt * 16 + lane] = f2bf(msum * icf);
        }
    }
}

// ---------------- kC: gates + experts + gated combine. 32 cells/block (verified round-2 version) ----
__global__ __launch_bounds__(256) void kC(const float* __restrict__ cur,
    const unsigned short* __restrict__ WT, const unsigned short* __restrict__ WgT,
    const unsigned short* __restrict__ agg_l, const unsigned short* __restrict__ agg_m,
    const unsigned short* __restrict__ agg_d,
    const float* __restrict__ b_local, const float* __restrict__ b_upd,
    const float* __restrict__ b_cnf, const float* __restrict__ bg1,
    const float* __restrict__ Wg2, const float* __restrict__ bg2,
    float* __restrict__ out)
{
    __shared__ __align__(16) unsigned short Wl[128][LDSB];
    __shared__ __align__(16) unsigned short Xc[32][LDSB];
    __shared__ __align__(16) unsigned short Xa[32][LDSB];
    __shared__ float hrelu[32][HGN + 4];
    __shared__ float glds[32][4];
    __shared__ float bl[DD], bu[DD], bc[DD];
    __shared__ float Wg2s[HGN * 3];
    __shared__ float bg2s[4];
    int t = threadIdx.x;
    int n0 = blockIdx.x * 32;
    int w = t >> 6, lane = t & 63;
    int mt = w & 1, colh = w >> 1;
    int lm = lane & 15, lq = lane >> 4;

    auto stageW = [&](int m, int koff) {
        const unsigned short* src = WT + m * 32768 + koff;
        for (int p = 0; p < 8; ++p) {
            int ch = p * 256 + t;
            int j = ch >> 4, i8 = (ch & 15) * 8;
            *(bf8v*)&Wl[j][i8] = *(const bf8v*)&src[j * 256 + i8];
        }
    };
    auto stageXa = [&](const unsigned short* src) {
        for (int p = 0; p < 2; ++p) {
            int idx = p * 256 + t;
            int r = idx >> 4, c8 = (idx & 15) * 8;
            bf8v v = {0, 0, 0, 0, 0, 0, 0, 0};
            if (n0 + r < NC) v = *(const bf8v*)&src[(size_t)(n0 + r) * DD + c8];
            *(bf8v*)&Xa[r][c8] = v;
        }
    };
    auto mfmaPass = [&](unsigned short (&X)[32][LDSB], f4v* acc) {
        for (int nt = 0; nt < 4; ++nt) {
            int col0 = colh * 64 + nt * 16;
            for (int s = 0; s < 4; ++s) {
                bf8v a = *(const bf8v*)&X[mt * 16 + lm][s * 32 + lq * 8];
                bf8v b = *(const bf8v*)&Wl[col0 + lm][s * 32 + lq * 8];
                acc[nt] = __builtin_amdgcn_mfma_f32_16x16x32_bf16(a, b, acc[nt], 0, 0, 0);
            }
        }
    };

    // ---- stage Xc, WgT -> Wl rows 0..63, biases, gating head weights ----
    for (int p = 0; p < 8; ++p) {
        int idx = p * 256 + t;
        int r = idx >> 6, c2 = (idx & 63) * 2;
        float2 v = {0.f, 0.f};
        if (n0 + r < NC) v = *(const float2*)&cur[(size_t)(n0 + r) * DD + c2];
        *(unsigned*)&Xc[r][c2] = pk2(v.x, v.y);
    }
    for (int p = 0; p < 4; ++p) {
        int ch = p * 256 + t;
        int j = ch >> 4, i8 = (ch & 15) * 8;
        *(bf8v*)&Wl[j][i8] = *(const bf8v*)&WgT[j * 128 + i8];
    }
    if (t < 128) { bl[t] = b_local[t]; bu[t] = b_upd[t]; bc[t] = b_cnf[t]; }
    for (int i = t; i < HGN * 3; i += 256) Wg2s[i] = Wg2[i];   // all 192 entries
    if (t < 3) bg2s[t] = bg2[t];
    __syncthreads();

    // ---- gates MFMA: wave w -> cols w*16..w*16+15 of 64 ----
    {
        int col0 = w * 16;
        float bg = bg1[col0 + lm];
        for (int mt2 = 0; mt2 < 2; ++mt2) {
            f4v acc = {0.f, 0.f, 0.f, 0.f};
            for (int s = 0; s < 4; ++s) {
                bf8v a = *(const bf8v*)&Xc[mt2 * 16 + lm][s * 32 + lq * 8];
                bf8v b = *(const bf8v*)&Wl[col0 + lm][s * 32 + lq * 8];
                acc = __builtin_amdgcn_mfma_f32_16x16x32_bf16(a, b, acc, 0, 0, 0);
            }
            for (int r = 0; r < 4; ++r)
                hrelu[mt2 * 16 + lq * 4 + r][col0 + lm] = fmaxf(acc[r] + bg, 0.f);
        }
    }
    __syncthreads();

    // ---- stage W_local k0 while 96 threads compute gate logits ----
    stageW(0, 0);
    if (t < 96) {
        int r = t / 3, e = t - r * 3;
        float s = bg2s[e];
        for (int g = 0; g < HGN; ++g) s += hrelu[r][g] * Wg2s[g * 3 + e];
        glds[r][e] = s;
    }
    __syncthreads();

    // ---- softmax (32 threads) overlapped with local-expert cur-half MFMA ----
    if (t < 32) {
        float l0 = glds[t][0], l1 = glds[t][1], l2 = glds[t][2];
        float m = fmaxf(l0, fmaxf(l1, l2));
        float e0 = expf(l0 - m), e1 = expf(l1 - m), e2 = expf(l2 - m);
        float inv = 1.f / (e0 + e1 + e2);
        glds[t][0] = e0 * inv; glds[t][1] = e1 * inv; glds[t][2] = e2 * inv;
    }
    f4v oacc[4], acc[4];
    for (int nt = 0; nt < 4; ++nt) oacc[nt] = (f4v){0.f, 0.f, 0.f, 0.f};

    // --- local expert ---
    for (int nt = 0; nt < 4; ++nt) acc[nt] = (f4v){0.f, 0.f, 0.f, 0.f};
    mfmaPass(Xc, acc);
    __syncthreads();
    stageW(0, 128); stageXa(agg_l);
    __syncthreads();
    mfmaPass(Xa, acc);
    for (int nt = 0; nt < 4; ++nt) {
        int col = colh * 64 + nt * 16 + lm;
        for (int r = 0; r < 4; ++r) {
            int row = mt * 16 + lq * 4 + r;
            oacc[nt][r] += glds[row][0] * tanhf(acc[nt][r] + bl[col]);
        }
    }

    // --- functional expert ---
    __syncthreads();
    stageW(2, 0);
    __syncthreads();
    for (int nt = 0; nt < 4; ++nt) acc[nt] = (f4v){0.f, 0.f, 0.f, 0.f};
    mfmaPass(Xc, acc);
    __syncthreads();
    stageW(2, 128); stageXa(agg_m);
    __syncthreads();
    mfmaPass(Xa, acc);
    for (int nt = 0; nt < 4; ++nt) {
        int col = colh * 64 + nt * 16 + lm;
        for (int r = 0; r < 4; ++r) {
            int row = mt * 16 + lq * 4 + r;
            oacc[nt][r] += glds[row][1] * tanhf(acc[nt][r] + bu[col]);
        }
    }

    // --- distant expert (CNF) ---
    __syncthreads();
    stageW(3, 128); stageXa(agg_d);
    __syncthreads();
    for (int nt = 0; nt < 4; ++nt) acc[nt] = (f4v){0.f, 0.f, 0.f, 0.f};
    mfmaPass(Xa, acc);
    f4v hd[4], s[4];
    for (int nt = 0; nt < 4; ++nt) {
        int col = colh * 64 + nt * 16 + lm;
        for (int r = 0; r < 4; ++r) {
            int row = mt * 16 + lq * 4 + r;
            int n = n0 + row;
            hd[nt][r] = acc[nt][r] + bc[col];
            s[nt][r] = (n < NC) ? cur[(size_t)n * DD + col] : 0.f;
        }
    }
    __syncthreads();
    stageW(3, 0);   // Wc1, persists across steps
    for (int step = 0; step < 3; ++step) {
        for (int nt = 0; nt < 4; ++nt) {
            int col = colh * 64 + nt * 16 + lm;
            for (int r = 0; r < 4; ++r) {
                int row = mt * 16 + lq * 4 + r;
                Xa[row][col] = f2bf(s[nt][r]);
            }
        }
        __syncthreads();
        for (int nt = 0; nt < 4; ++nt) acc[nt] = (f4v){0.f, 0.f, 0.f, 0.f};
        mfmaPass(Xa, acc);
        for (int nt = 0; nt < 4; ++nt)
            for (int r = 0; r < 4; ++r)
                s[nt][r] += DTC * tanhf(acc[nt][r] + hd[nt][r]);
        __syncthreads();
    }

    // --- combine + store ---
    for (int nt = 0; nt < 4; ++nt) {
        int col = colh * 64 + nt * 16 + lm;
        for (int r = 0; r < 4; ++r) {
            int row = mt * 16 + lq * 4 + r;
            int n = n0 + row;
            if (n < NC) out[(size_t)n * DD + col] = oacc[nt][r] + glds[row][2] * s[nt][r];
        }
    }
}

extern "C" void kernel_launch(void* const* d_in, const int* in_sizes, int n_in,
                              void* d_out, int out_size, void* d_ws, size_t ws_size,
                              hipStream_t stream) {
    const float* cur     = (const float*)d_in[0];
    const float* nbr     = (const float*)d_in[1];
    const int*   conn    = (const int*)d_in[2];
    const float* W_local = (const float*)d_in[3];
    const float* b_local = (const float*)d_in[4];
    const float* W_msg   = (const float*)d_in[5];
    const float* b_msg   = (const float*)d_in[6];
    const float* W_upd   = (const float*)d_in[7];
    const float* b_upd   = (const float*)d_in[8];
    const float* W_cnf   = (const float*)d_in[9];
    const float* b_cnf   = (const float*)d_in[10];
    const float* Wg1     = (const float*)d_in[11];
    const float* bg1     = (const float*)d_in[12];
    const float* Wg2     = (const float*)d_in[13];
    const float* bg2     = (const float*)d_in[14];
    float* out = (float*)d_out;

    char* ws = (char*)d_ws;
    unsigned short* WT   = (unsigned short*)ws;                      // 262144 B
    unsigned short* WgT  = (unsigned short*)(ws + 262144);           // 16384 B
    unsigned short* aggl = (unsigned short*)(ws + 278528);           // 5038848 B each
    unsigned short* aggm = aggl + (size_t)NC * DD;
    unsigned short* aggd = aggm + (size_t)NC * DD;

    hipLaunchKernelGGL(k_prep, dim3(544), dim3(256), 0, stream,
                       W_local, W_msg, W_upd, W_cnf, Wg1, WT, WgT);
    hipLaunchKernelGGL(kE, dim3((NC + CPB - 1) / CPB), dim3(256), 0, stream,
                       cur, nbr, conn, WT, b_msg, aggl, aggm, aggd);
    hipLaunchKernelGGL(kC, dim3(616), dim3(256), 0, stream, cur, WT, WgT, aggl, aggm, aggd,
                       b_local, b_upd, b_cnf, bg1, Wg2, bg2, out);
}

// Round 8
// 475.035 us; speedup vs baseline: 1.0362x; 1.0362x over previous
//
#include <hip/hip_runtime.h>
#include <math.h>

#define NC 19683
#define KN 26
#define DD 128
#define HGN 64
#define LDSB 136
#define DTC 0.1f
#define CPB 40         // kE: cells per block (processed one at a time, block-wide)

using bf8v = __attribute__((ext_vector_type(8))) short;
using f4v  = __attribute__((ext_vector_type(4))) float;

typedef __attribute__((address_space(1))) const void g_void;
typedef __attribute__((address_space(3))) void l_void;

#define WAITV(N) asm volatile("s_waitcnt vmcnt(" #N ")" ::: "memory")
#define WAITL()  asm volatile("s_waitcnt lgkmcnt(0)" ::: "memory")

static __device__ __forceinline__ unsigned short f2bf(float x) {
    union { float f; unsigned u; } v; v.f = x;
    unsigned r = v.u + 0x7fffu + ((v.u >> 16) & 1u);
    return (unsigned short)(r >> 16);
}
static __device__ __forceinline__ unsigned pk2(float a, float b) {
    return ((unsigned)f2bf(a)) | (((unsigned)f2bf(b)) << 16);
}
static __device__ __forceinline__ float bf2f(unsigned short u) {
    union { float f; unsigned v; } w; w.v = ((unsigned)u) << 16; return w.f;
}
// pack 8 f32 (two float4) -> bf8v via v_cvt_pk_bf16_f32 (RNE, matches f2bf)
static __device__ __forceinline__ bf8v cvt8(float4 lo, float4 hi) {
    union { bf8v v; unsigned d[4]; } u;
    asm volatile("v_cvt_pk_bf16_f32 %0, %1, %2" : "=v"(u.d[0]) : "v"(lo.x), "v"(lo.y));
    asm volatile("v_cvt_pk_bf16_f32 %0, %1, %2" : "=v"(u.d[1]) : "v"(lo.z), "v"(lo.w));
    asm volatile("v_cvt_pk_bf16_f32 %0, %1, %2" : "=v"(u.d[2]) : "v"(hi.x), "v"(hi.y));
    asm volatile("v_cvt_pk_bf16_f32 %0, %1, %2" : "=v"(u.d[3]) : "v"(hi.z), "v"(hi.w));
    return u.v;
}

// ---------------- prep: transpose 4x [256,128] f32 weights -> [128][256] bf16; Wg1 -> [64][128] bf16 ----
__global__ __launch_bounds__(256) void k_prep(const float* __restrict__ Wl,
    const float* __restrict__ Wm, const float* __restrict__ Wu,
    const float* __restrict__ Wc, const float* __restrict__ Wg1,
    unsigned short* __restrict__ WT, unsigned short* __restrict__ WgT)
{
    int idx = blockIdx.x * 256 + threadIdx.x;   // 544*256 = 139264 exact
    if (idx < 131072) {
        int m = idx >> 15;
        int r = idx & 32767;
        int j = r >> 8;     // 0..127 output col
        int i = r & 255;    // 0..255 k
        const float* src = (m == 0) ? Wl : (m == 1) ? Wm : (m == 2) ? Wu : Wc;
        WT[idx] = f2bf(src[i * DD + j]);
    } else {
        int idx2 = idx - 131072;        // 0..8191
        int col = idx2 >> 7;            // 0..63
        int k = idx2 & 127;             // 0..127
        WgT[idx2] = f2bf(Wg1[k * HGN + col]);
    }
}

// ---------------- kE: P + edge pass. One cell per block-wide group, 4-wave cooperative DMA,
//                  double-buffered, counted vmcnt + raw barriers (m97/8-phase pattern) ----------------
// LDS arena: [0,34816)       Wt  = Wm2 bf16 [128][LDSB]
//            [34816,48128)   buf0: 26 rows x 512B f32 (XOR-swizzled source)
//            [48128,61440)   buf1
//            [61440,73728)   Pb  = bf16 [48][128]
//            [73728,77888)   connL int[CPB*KN]
__global__ __launch_bounds__(256, 2) void kE(const float* __restrict__ cur,
    const float* __restrict__ nbr, const int* __restrict__ conn,
    const unsigned short* __restrict__ WT, const float* __restrict__ b_msg,
    unsigned short* __restrict__ agg_l, unsigned short* __restrict__ agg_m,
    unsigned short* __restrict__ agg_d)
{
    __shared__ __align__(16) char LDSA[77888];
    unsigned short* Wt   = (unsigned short*)LDSA;
    unsigned short* Pb   = (unsigned short*)(LDSA + 61440);
    int*            connL = (int*)(LDSA + 73728);

    int t = threadIdx.x;
    int n0 = blockIdx.x * CPB;
    int ng = NC - n0; if (ng > CPB) ng = CPB;   // cells in this block (uniform)
    int w = t >> 6, lane = t & 63;
    int lm = lane & 15, lq = lane >> 4;
    int rlo = lane >> 5;                        // sub-row within 1KB DMA
    unsigned wb = (unsigned)(lane & 31) * 16;   // within-row byte (pre-swizzle)

    // ---- prologue: Wt <- Wm2 ----
    {
        const unsigned short* Wm2 = WT + 32768 + 128;
        for (int p = 0; p < 8; ++p) {
            int ch = p * 256 + t;
            int j = ch >> 4, i8 = (ch & 15) * 8;
            *(bf8v*)&Wt[j * LDSB + i8] = *(const bf8v*)&Wm2[j * 256 + i8];
        }
    }
    // ---- prologue: connL <- conn block ----
    for (int idx = t; idx < ng * KN; idx += 256)
        connL[idx] = conn[(size_t)n0 * KN + idx];
    // ---- prologue: P-pass. 3 row-tiles (rows 0..47 = cells), A from global cur, B from L2 Wm1 ----
    {
        const unsigned short* Wm1 = WT + 32768;
        for (int rt = 0; rt < 3; ++rt) {
            int gr = n0 + rt * 16 + lm; if (gr >= NC) gr = NC - 1;
            const float* rb = &cur[(size_t)gr * DD];
            bf8v afrP[4];
            #pragma unroll
            for (int s = 0; s < 4; ++s) {
                float4 lo = *(const float4*)&rb[s * 32 + lq * 8];
                float4 hi = *(const float4*)&rb[s * 32 + lq * 8 + 4];
                afrP[s] = cvt8(lo, hi);
            }
            for (int ntp = 0; ntp < 2; ++ntp) {
                int col0 = w * 32 + ntp * 16;
                float bm = b_msg[col0 + lm];
                const unsigned short* bb = &Wm1[(col0 + lm) * 256 + lq * 8];
                f4v acc = {0.f, 0.f, 0.f, 0.f};
                #pragma unroll
                for (int s = 0; s < 4; ++s) {
                    bf8v b = *(const bf8v*)&bb[s * 32];
                    acc = __builtin_amdgcn_mfma_f32_16x16x32_bf16(afrP[s], b, acc, 0, 0, 0);
                }
                for (int r = 0; r < 4; ++r) {
                    int row = rt * 16 + lq * 4 + r;
                    Pb[row * DD + col0 + lm] = f2bf(acc[r] + bm);
                }
            }
        }
    }
    __syncthreads();            // Wt/Pb/connL visible; full drain (prologue only)

    // ---- cooperative DMA stage of cell i: 13 x 1KB, wave w takes j = w, w+4, ... ----
    auto stage = [&](int i) {
        const char* cb = (const char*)(nbr + (size_t)(n0 + i) * KN * DD);
        char* slot = LDSA + 34816 + ((i & 1) ? 13312 : 0);
        for (int j = w; j < 13; j += 4) {
            int row = 2 * j + rlo;
            const char* src = cb + (size_t)row * 512 + (wb ^ ((unsigned)(row & 7) << 4));
            __builtin_amdgcn_global_load_lds((g_void*)src, (l_void*)(slot + j * 1024), 16, 0, 0);
        }
    };

    stage(0);
    for (int g = 0; g < ng; ++g) {
        // issue next cell's DMA, then wait for ONLY the current cell's data (counted vmcnt)
        if (g + 1 < ng) {
            stage(g + 1);
            if (w == 0) { WAITV(4); } else { WAITV(3); }
        } else {
            WAITV(0);
        }
        __builtin_amdgcn_sched_barrier(0);
        __builtin_amdgcn_s_barrier();           // all waves' shares of cell g landed

        const char* slot = LDSA + 34816 + ((g & 1) ? 13312 : 0);
        size_t n = n0 + g;
        int ct = (lane < KN) ? connL[g * KN + lane] : 3;
        unsigned long long mlb = __ballot(ct == 0);
        unsigned long long mfb = __ballot(ct == 1);
        unsigned long long mdb = __ballot(ct == 2);
        float icf = 1.f / fmaxf((float)__builtin_popcountll(mfb), 1.f);

        // ---- rotating sums wave: agg_l / agg_d (masked column means) ----
        if (w == (g & 3)) {
            float icl = 1.f / fmaxf((float)__builtin_popcountll(mlb), 1.f);
            float icd = 1.f / fmaxf((float)__builtin_popcountll(mdb), 1.f);
            float slx = 0.f, sly = 0.f, sdx = 0.f, sdy = 0.f;
            #pragma unroll
            for (int k = 0; k < KN; ++k) {
                float2 v = *(const float2*)(slot + (size_t)k * 512 +
                           (((unsigned)lane * 8) ^ ((unsigned)(k & 7) << 4)));
                if ((mlb >> k) & 1) { slx += v.x; sly += v.y; }
                if ((mdb >> k) & 1) { sdx += v.x; sdy += v.y; }
            }
            *(unsigned*)&agg_l[n * DD + lane * 2] = pk2(slx * icl, sly * icl);
            *(unsigned*)&agg_d[n * DD + lane * 2] = pk2(sdx * icd, sdy * icd);
        }

        // ---- A-fragments from slot (swizzled) + cvt. rows 26..31 read pad (masked by mfb) ----
        bf8v afr[2][4];
        #pragma unroll
        for (int mt2 = 0; mt2 < 2; ++mt2) {
            int row = mt2 * 16 + lm;
            unsigned X = (unsigned)(row & 7) << 4;
            const char* rb = slot + (size_t)row * 512;
            #pragma unroll
            for (int s = 0; s < 4; ++s) {
                unsigned b0 = (unsigned)(s * 128 + lq * 32);
                float4 lo = *(const float4*)(rb + (b0 ^ X));
                float4 hi = *(const float4*)(rb + ((b0 + 16) ^ X));
                afr[mt2][s] = cvt8(lo, hi);
            }
        }

        // ---- this wave's 2 col-tiles of the cell's msg GEMM + masked relu-sum ----
        #pragma unroll
        for (int ntp = 0; ntp < 2; ++ntp) {
            int nt = w * 2 + ntp;
            float pv = bf2f(Pb[g * DD + nt * 16 + lm]);
            f4v a0 = {0.f, 0.f, 0.f, 0.f}, a1 = {0.f, 0.f, 0.f, 0.f};
            #pragma unroll
            for (int s = 0; s < 4; ++s) {
                bf8v b = *(const bf8v*)&Wt[(nt * 16 + lm) * LDSB + s * 32 + lq * 8];
                a0 = __builtin_amdgcn_mfma_f32_16x16x32_bf16(afr[0][s], b, a0, 0, 0, 0);
                a1 = __builtin_amdgcn_mfma_f32_16x16x32_bf16(afr[1][s], b, a1, 0, 0, 0);
            }
            float msum = 0.f;
            #pragma unroll
            for (int r = 0; r < 4; ++r) {
                int rr = lq * 4 + r;
                if ((mfb >> rr) & 1) msum += fmaxf(pv + a0[r], 0.f);
                int rr2 = 16 + lq * 4 + r;
                if ((mfb >> rr2) & 1) msum += fmaxf(pv + a1[r], 0.f);
            }
            msum += __shfl_xor(msum, 16, 64);
            msum += __shfl_xor(msum, 32, 64);
            if (lane < 16) agg_m[n * DD + nt * 16 + lane] = f2bf(msum * icf);
        }

        WAITL();                                // my ds_reads of buf[g&1] drained
        __builtin_amdgcn_s_barrier();           // all waves done with buf[g&1]
    }
}

// ---------------- kC: gates + experts + gated combine. 32 cells/block (verified round-2 version) ----
__global__ __launch_bounds__(256) void kC(const float* __restrict__ cur,
    const unsigned short* __restrict__ WT, const unsigned short* __restrict__ WgT,
    const unsigned short* __restrict__ agg_l, const unsigned short* __restrict__ agg_m,
    const unsigned short* __restrict__ agg_d,
    const float* __restrict__ b_local, const float* __restrict__ b_upd,
    const float* __restrict__ b_cnf, const float* __restrict__ bg1,
    const float* __restrict__ Wg2, const float* __restrict__ bg2,
    float* __restrict__ out)
{
    __shared__ __align__(16) unsigned short Wl[128][LDSB];
    __shared__ __align__(16) unsigned short Xc[32][LDSB];
    __shared__ __align__(16) unsigned short Xa[32][LDSB];
    __shared__ float hrelu[32][HGN + 4];
    __shared__ float glds[32][4];
    __shared__ float bl[DD], bu[DD], bc[DD];
    __shared__ float Wg2s[HGN * 3];
    __shared__ float bg2s[4];
    int t = threadIdx.x;
    int n0 = blockIdx.x * 32;
    int w = t >> 6, lane = t & 63;
    int mt = w & 1, colh = w >> 1;
    int lm = lane & 15, lq = lane >> 4;

    auto stageW = [&](int m, int koff) {
        const unsigned short* src = WT + m * 32768 + koff;
        for (int p = 0; p < 8; ++p) {
            int ch = p * 256 + t;
            int j = ch >> 4, i8 = (ch & 15) * 8;
            *(bf8v*)&Wl[j][i8] = *(const bf8v*)&src[j * 256 + i8];
        }
    };
    auto stageXa = [&](const unsigned short* src) {
        for (int p = 0; p < 2; ++p) {
            int idx = p * 256 + t;
            int r = idx >> 4, c8 = (idx & 15) * 8;
            bf8v v = {0, 0, 0, 0, 0, 0, 0, 0};
            if (n0 + r < NC) v = *(const bf8v*)&src[(size_t)(n0 + r) * DD + c8];
            *(bf8v*)&Xa[r][c8] = v;
        }
    };
    auto mfmaPass = [&](unsigned short (&X)[32][LDSB], f4v* acc) {
        for (int nt = 0; nt < 4; ++nt) {
            int col0 = colh * 64 + nt * 16;
            for (int s = 0; s < 4; ++s) {
                bf8v a = *(const bf8v*)&X[mt * 16 + lm][s * 32 + lq * 8];
                bf8v b = *(const bf8v*)&Wl[col0 + lm][s * 32 + lq * 8];
                acc[nt] = __builtin_amdgcn_mfma_f32_16x16x32_bf16(a, b, acc[nt], 0, 0, 0);
            }
        }
    };

    // ---- stage Xc, WgT -> Wl rows 0..63, biases, gating head weights ----
    for (int p = 0; p < 8; ++p) {
        int idx = p * 256 + t;
        int r = idx >> 6, c2 = (idx & 63) * 2;
        float2 v = {0.f, 0.f};
        if (n0 + r < NC) v = *(const float2*)&cur[(size_t)(n0 + r) * DD + c2];
        *(unsigned*)&Xc[r][c2] = pk2(v.x, v.y);
    }
    for (int p = 0; p < 4; ++p) {
        int ch = p * 256 + t;
        int j = ch >> 4, i8 = (ch & 15) * 8;
        *(bf8v*)&Wl[j][i8] = *(const bf8v*)&WgT[j * 128 + i8];
    }
    if (t < 128) { bl[t] = b_local[t]; bu[t] = b_upd[t]; bc[t] = b_cnf[t]; }
    for (int i = t; i < HGN * 3; i += 256) Wg2s[i] = Wg2[i];   // all 192 entries
    if (t < 3) bg2s[t] = bg2[t];
    __syncthreads();

    // ---- gates MFMA: wave w -> cols w*16..w*16+15 of 64 ----
    {
        int col0 = w * 16;
        float bg = bg1[col0 + lm];
        for (int mt2 = 0; mt2 < 2; ++mt2) {
            f4v acc = {0.f, 0.f, 0.f, 0.f};
            for (int s = 0; s < 4; ++s) {
                bf8v a = *(const bf8v*)&Xc[mt2 * 16 + lm][s * 32 + lq * 8];
                bf8v b = *(const bf8v*)&Wl[col0 + lm][s * 32 + lq * 8];
                acc = __builtin_amdgcn_mfma_f32_16x16x32_bf16(a, b, acc, 0, 0, 0);
            }
            for (int r = 0; r < 4; ++r)
                hrelu[mt2 * 16 + lq * 4 + r][col0 + lm] = fmaxf(acc[r] + bg, 0.f);
        }
    }
    __syncthreads();

    // ---- stage W_local k0 while 96 threads compute gate logits ----
    stageW(0, 0);
    if (t < 96) {
        int r = t / 3, e = t - r * 3;
        float s = bg2s[e];
        for (int g = 0; g < HGN; ++g) s += hrelu[r][g] * Wg2s[g * 3 + e];
        glds[r][e] = s;
    }
    __syncthreads();

    // ---- softmax (32 threads) overlapped with local-expert cur-half MFMA ----
    if (t < 32) {
        float l0 = glds[t][0], l1 = glds[t][1], l2 = glds[t][2];
        float m = fmaxf(l0, fmaxf(l1, l2));
        float e0 = expf(l0 - m), e1 = expf(l1 - m), e2 = expf(l2 - m);
        float inv = 1.f / (e0 + e1 + e2);
        glds[t][0] = e0 * inv; glds[t][1] = e1 * inv; glds[t][2] = e2 * inv;
    }
    f4v oacc[4], acc[4];
    for (int nt = 0; nt < 4; ++nt) oacc[nt] = (f4v){0.f, 0.f, 0.f, 0.f};

    // --- local expert ---
    for (int nt = 0; nt < 4; ++nt) acc[nt] = (f4v){0.f, 0.f, 0.f, 0.f};
    mfmaPass(Xc, acc);
    __syncthreads();
    stageW(0, 128); stageXa(agg_l);
    __syncthreads();
    mfmaPass(Xa, acc);
    for (int nt = 0; nt < 4; ++nt) {
        int col = colh * 64 + nt * 16 + lm;
        for (int r = 0; r < 4; ++r) {
            int row = mt * 16 + lq * 4 + r;
            oacc[nt][r] += glds[row][0] * tanhf(acc[nt][r] + bl[col]);
        }
    }

    // --- functional expert ---
    __syncthreads();
    stageW(2, 0);
    __syncthreads();
    for (int nt = 0; nt < 4; ++nt) acc[nt] = (f4v){0.f, 0.f, 0.f, 0.f};
    mfmaPass(Xc, acc);
    __syncthreads();
    stageW(2, 128); stageXa(agg_m);
    __syncthreads();
    mfmaPass(Xa, acc);
    for (int nt = 0; nt < 4; ++nt) {
        int col = colh * 64 + nt * 16 + lm;
        for (int r = 0; r < 4; ++r) {
            int row = mt * 16 + lq * 4 + r;
            oacc[nt][r] += glds[row][1] * tanhf(acc[nt][r] + bu[col]);
        }
    }

    // --- distant expert (CNF) ---
    __syncthreads();
    stageW(3, 128); stageXa(agg_d);
    __syncthreads();
    for (int nt = 0; nt < 4; ++nt) acc[nt] = (f4v){0.f, 0.f, 0.f, 0.f};
    mfmaPass(Xa, acc);
    f4v hd[4], s[4];
    for (int nt = 0; nt < 4; ++nt) {
        int col = colh * 64 + nt * 16 + lm;
        for (int r = 0; r < 4; ++r) {
            int row = mt * 16 + lq * 4 + r;
            int n = n0 + row;
            hd[nt][r] = acc[nt][r] + bc[col];
            s[nt][r] = (n < NC) ? cur[(size_t)n * DD + col] : 0.f;
        }
    }
    __syncthreads();
    stageW(3, 0);   // Wc1, persists across steps
    for (int step = 0; step < 3; ++step) {
        for (int nt = 0; nt < 4; ++nt) {
            int col = colh * 64 + nt * 16 + lm;
            for (int r = 0; r < 4; ++r) {
                int row = mt * 16 + lq * 4 + r;
                Xa[row][col] = f2bf(s[nt][r]);
            }
        }
        __syncthreads();
        for (int nt = 0; nt < 4; ++nt) acc[nt] = (f4v){0.f, 0.f, 0.f, 0.f};
        mfmaPass(Xa, acc);
        for (int nt = 0; nt < 4; ++nt)
            for (int r = 0; r < 4; ++r)
                s[nt][r] += DTC * tanhf(acc[nt][r] + hd[nt][r]);
        __syncthreads();
    }

    // --- combine + store ---
    for (int nt = 0; nt < 4; ++nt) {
        int col = colh * 64 + nt * 16 + lm;
        for (int r = 0; r < 4; ++r) {
            int row = mt * 16 + lq * 4 + r;
            int n = n0 + row;
            if (n < NC) out[(size_t)n * DD + col] = oacc[nt][r] + glds[row][2] * s[nt][r];
        }
    }
}

extern "C" void kernel_launch(void* const* d_in, const int* in_sizes, int n_in,
                              void* d_out, int out_size, void* d_ws, size_t ws_size,
                              hipStream_t stream) {
    const float* cur     = (const float*)d_in[0];
    const float* nbr     = (const float*)d_in[1];
    const int*   conn    = (const int*)d_in[2];
    const float* W_local = (const float*)d_in[3];
    const float* b_local = (const float*)d_in[4];
    const float* W_msg   = (const float*)d_in[5];
    const float* b_msg   = (const float*)d_in[6];
    const float* W_upd   = (const float*)d_in[7];
    const float* b_upd   = (const float*)d_in[8];
    const float* W_cnf   = (const float*)d_in[9];
    const float* b_cnf   = (const float*)d_in[10];
    const float* Wg1     = (const float*)d_in[11];
    const float* bg1     = (const float*)d_in[12];
    const float* Wg2     = (const float*)d_in[13];
    const float* bg2     = (const float*)d_in[14];
    float* out = (float*)d_out;

    char* ws = (char*)d_ws;
    unsigned short* WT   = (unsigned short*)ws;                      // 262144 B
    unsigned short* WgT  = (unsigned short*)(ws + 262144);           // 16384 B
    unsigned short* aggl = (unsigned short*)(ws + 278528);           // 5038848 B each
    unsigned short* aggm = aggl + (size_t)NC * DD;
    unsigned short* aggd = aggm + (size_t)NC * DD;

    hipLaunchKernelGGL(k_prep, dim3(544), dim3(256), 0, stream,
                       W_local, W_msg, W_upd, W_cnf, Wg1, WT, WgT);
    hipLaunchKernelGGL(kE, dim3((NC + CPB - 1) / CPB), dim3(256), 0, stream,
                       cur, nbr, conn, WT, b_msg, aggl, aggm, aggd);
    hipLaunchKernelGGL(kC, dim3(616), dim3(256), 0, stream, cur, WT, WgT, aggl, aggm, aggd,
                       b_local, b_upd, b_cnf, bg1, Wg2, bg2, out);
}